// Round 1
// baseline (503.014 us; speedup 1.0000x reference)
//
#include <hip/hip_runtime.h>
#include <math.h>
#include <stdint.h>
#include <stddef.h>

typedef __bf16 bf16;
typedef __bf16 bf16x8 __attribute__((ext_vector_type(8)));
typedef __bf16 bf16x4 __attribute__((ext_vector_type(4)));
typedef float  f32x4  __attribute__((ext_vector_type(4)));
typedef float  f32x4v __attribute__((ext_vector_type(4)));

typedef __attribute__((address_space(1))) const void* as1cv;
typedef __attribute__((address_space(3))) void*       as3v;

__device__ __forceinline__ f32x4 mfma16(bf16x8 a, bf16x8 b, f32x4 c) {
  return __builtin_amdgcn_mfma_f32_16x16x32_bf16(a, b, c, 0, 0, 0);
}

__device__ __forceinline__ void gload_lds16(const bf16* g, bf16* l) {
  __builtin_amdgcn_global_load_lds((as1cv)g, (as3v)l, 16, 0, 0);
}

// ---------------------------------------------------------------- convert
__global__ void cvt_f32_bf16(const float* __restrict__ src, bf16* __restrict__ dst, int n4) {
  int i = blockIdx.x * blockDim.x + threadIdx.x;
  int stride = gridDim.x * blockDim.x;
  for (; i < n4; i += stride) {
    f32x4v v = ((const f32x4v*)src)[i];
    bf16x4 o;
    o[0] = (bf16)v[0]; o[1] = (bf16)v[1]; o[2] = (bf16)v[2]; o[3] = (bf16)v[3];
    ((bf16x4*)dst)[i] = o;
  }
}

// ---------------------------------------------------------------- GEMM  C = A @ B^T
// A: M x K row-major (lda), B: N x K row-major (ldb == K). 128x128 tile, BK=64,
// global_load_lds width-16 staging with XOR chunk swizzle (source+read same involution).
template<bool OUTF32>
__global__ __launch_bounds__(256) void gemm_bt(
    const bf16* __restrict__ A, int lda,
    const bf16* __restrict__ B, int K,
    float* __restrict__ Cf, bf16* __restrict__ Cb, int ldc,
    const float* __restrict__ bias, int bias_n)
{
  __shared__ __align__(16) bf16 Al[128 * 64];
  __shared__ __align__(16) bf16 Bl[128 * 64];
  const int tid = threadIdx.x;
  const int l = tid & 63;
  const int wid = tid >> 6;
  const int wr = wid >> 1, wc = wid & 1;
  const int m0 = blockIdx.y * 128, n0 = blockIdx.x * 128;
  const int lr = l & 15, lg = l >> 4;

  f32x4 z = {0.f, 0.f, 0.f, 0.f};
  f32x4 acc[4][4];
#pragma unroll
  for (int i = 0; i < 4; ++i)
#pragma unroll
    for (int j = 0; j < 4; ++j) acc[i][j] = z;

  for (int k0 = 0; k0 < K; k0 += 64) {
    __syncthreads();
#pragma unroll
    for (int it = 0; it < 4; ++it) {
      int chunk = it * 256 + tid;          // 1024 chunks of 16B (128 rows x 8)
      int row = chunk >> 3;
      int scb = (chunk & 7) ^ (row & 7);   // inverse-swizzled source chunk
      gload_lds16(A + (size_t)(m0 + row) * lda + k0 + scb * 8, Al + chunk * 8);
    }
#pragma unroll
    for (int it = 0; it < 4; ++it) {
      int chunk = it * 256 + tid;
      int row = chunk >> 3;
      int scb = (chunk & 7) ^ (row & 7);
      gload_lds16(B + (size_t)(n0 + row) * K + k0 + scb * 8, Bl + chunk * 8);
    }
    __syncthreads();   // drains vmcnt(0): LDS tiles ready
#pragma unroll
    for (int kk = 0; kk < 2; ++kk) {
      bf16x8 af[4], bfr[4];
#pragma unroll
      for (int i = 0; i < 4; ++i) {
        int row = wr * 64 + i * 16 + lr;
        int cq = kk * 4 + lg;
        af[i] = *(const bf16x8*)(Al + row * 64 + ((cq ^ (row & 7)) * 8));
      }
#pragma unroll
      for (int j = 0; j < 4; ++j) {
        int row = wc * 64 + j * 16 + lr;
        int cq = kk * 4 + lg;
        bfr[j] = *(const bf16x8*)(Bl + row * 64 + ((cq ^ (row & 7)) * 8));
      }
#pragma unroll
      for (int i = 0; i < 4; ++i)
#pragma unroll
        for (int j = 0; j < 4; ++j)
          acc[i][j] = mfma16(af[i], bfr[j], acc[i][j]);
    }
  }

#pragma unroll
  for (int i = 0; i < 4; ++i)
#pragma unroll
    for (int j = 0; j < 4; ++j)
#pragma unroll
      for (int r = 0; r < 4; ++r) {
        int row = m0 + wr * 64 + i * 16 + lg * 4 + r;
        int col = n0 + wc * 64 + j * 16 + lr;
        float v = acc[i][j][r];
        if (bias != nullptr && col < bias_n) v += bias[col];
        if (OUTF32) Cf[(size_t)row * ldc + col] = v;
        else        Cb[(size_t)row * ldc + col] = (bf16)v;
      }
}

// ---------------------------------------------------------------- RoPE
// QA: 2048 x 3072 ([Qfull | Qr_pre]); c_all: 2048 x 2176 (kr_pre at col 2048)
__global__ void rope_kernel(const bf16* __restrict__ QA, const bf16* __restrict__ c_all,
                            const float* __restrict__ cosb, const float* __restrict__ sinb,
                            bf16* __restrict__ Qr, bf16* __restrict__ Kr)
{
  int t = blockIdx.x;
  for (int idx = threadIdx.x; idx < 544; idx += 256) {
    if (idx < 512) {
      int h = idx >> 5, p = idx & 31;
      float x1 = (float)QA[(size_t)t * 3072 + 2048 + h * 64 + p];
      float x2 = (float)QA[(size_t)t * 3072 + 2048 + h * 64 + 32 + p];
      float c = cosb[t * 32 + p], s = sinb[t * 32 + p];
      Qr[(size_t)t * 1024 + h * 64 + p]      = (bf16)( x1 * c + x2 * s);
      Qr[(size_t)t * 1024 + h * 64 + 32 + p] = (bf16)(-x1 * s + x2 * c);
    } else {
      int p = idx - 512;
      float x1 = (float)c_all[(size_t)t * 2176 + 2048 + p];
      float x2 = (float)c_all[(size_t)t * 2176 + 2048 + 32 + p];
      float c = cosb[t * 32 + p], s = sinb[t * 32 + p];
      Kr[(size_t)t * 64 + p]      = (bf16)( x1 * c + x2 * s);
      Kr[(size_t)t * 64 + 32 + p] = (bf16)(-x1 * s + x2 * c);
    }
  }
}

// ---------------------------------------------------------------- V transpose
// Vt[c][t] = KV[t][2048 + c]   (c,t in 0..2047)
__global__ void transpose_v(const bf16* __restrict__ KV, bf16* __restrict__ Vt) {
  __shared__ bf16 tile[32][33];
  int tx = threadIdx.x & 31, ty = threadIdx.x >> 5;   // 256 thr: ty 0..7
  int t0 = blockIdx.x * 32, c0 = blockIdx.y * 32;
#pragma unroll
  for (int r = 0; r < 4; ++r)
    tile[ty + r * 8][tx] = KV[(size_t)(t0 + ty + r * 8) * 4096 + 2048 + c0 + tx];
  __syncthreads();
#pragma unroll
  for (int r = 0; r < 4; ++r)
    Vt[(size_t)(c0 + ty + r * 8) * 2048 + t0 + tx] = tile[tx][ty + r * 8];
}

// ---------------------------------------------------------------- flash attention
// 1 wave/block, 32 q-rows, KT=32, d_qk=192 (128 latent + 64 rope), d_v=128, causal.
__global__ __launch_bounds__(64) void attn_kernel(
    const bf16* __restrict__ QA,  // 2048 x 3072
    const bf16* __restrict__ Qr,  // 2048 x 1024
    const bf16* __restrict__ KV,  // 2048 x 4096 ([Kfull|Vfull])
    const bf16* __restrict__ Kr,  // 2048 x 64
    const bf16* __restrict__ Vt,  // 2048(c=h*128+d) x 2048(t)
    bf16* __restrict__ heads)     // 2048 x 2048
{
  const int l = threadIdx.x;
  const int h = blockIdx.y;
  const int qt = gridDim.x - 1 - blockIdx.x;  // longest tiles dispatched first
  const int q0 = qt * 32;
  const int lr = l & 15, lg = l >> 4;
  __shared__ __align__(16) bf16 P_lds[2][16][32];

  const float scale = 0.041666666666666664f;  // 1/sqrt(576)
  f32x4 z = {0.f, 0.f, 0.f, 0.f};

  bf16x8 aq[2][6];
#pragma unroll
  for (int rf = 0; rf < 2; ++rf) {
    int row = q0 + rf * 16 + lr;
#pragma unroll
    for (int kc = 0; kc < 4; ++kc)
      aq[rf][kc] = *(const bf16x8*)&QA[(size_t)row * 3072 + h * 128 + kc * 32 + lg * 8];
#pragma unroll
    for (int kc = 4; kc < 6; ++kc)
      aq[rf][kc] = *(const bf16x8*)&Qr[(size_t)row * 1024 + h * 64 + (kc - 4) * 32 + lg * 8];
  }

  float m_run[2][4], l_run[2][4];
  f32x4 acc[2][8];
#pragma unroll
  for (int rf = 0; rf < 2; ++rf) {
#pragma unroll
    for (int r = 0; r < 4; ++r) { m_run[rf][r] = -INFINITY; l_run[rf][r] = 0.f; }
#pragma unroll
    for (int j = 0; j < 8; ++j) acc[rf][j] = z;
  }

  for (int st = 0; st <= qt; ++st) {
    int s0 = st * 32;
    f32x4 sc[2][2];
    sc[0][0] = z; sc[0][1] = z; sc[1][0] = z; sc[1][1] = z;
#pragma unroll
    for (int c = 0; c < 2; ++c) {
      int krow = s0 + c * 16 + lr;
#pragma unroll
      for (int kc = 0; kc < 6; ++kc) {
        bf16x8 bk = (kc < 4)
          ? *(const bf16x8*)&KV[(size_t)krow * 4096 + h * 128 + kc * 32 + lg * 8]
          : *(const bf16x8*)&Kr[(size_t)krow * 64 + (kc - 4) * 32 + lg * 8];
        sc[0][c] = mfma16(aq[0][kc], bk, sc[0][c]);
        sc[1][c] = mfma16(aq[1][kc], bk, sc[1][c]);
      }
    }
    float p[2][2][4];
#pragma unroll
    for (int rf = 0; rf < 2; ++rf) {
      float alpha[4];
#pragma unroll
      for (int r = 0; r < 4; ++r) {
        int row = q0 + rf * 16 + lg * 4 + r;
        float v0 = sc[rf][0][r] * scale;
        float v1 = sc[rf][1][r] * scale;
        if (s0 + lr > row)      v0 = -INFINITY;
        if (s0 + 16 + lr > row) v1 = -INFINITY;
        float mx = fmaxf(v0, v1);
#pragma unroll
        for (int m = 1; m < 16; m <<= 1) mx = fmaxf(mx, __shfl_xor(mx, m, 64));
        float mnew = fmaxf(m_run[rf][r], mx);
        float al = __expf(m_run[rf][r] - mnew);
        float p0 = __expf(v0 - mnew);
        float p1 = __expf(v1 - mnew);
        float sum = p0 + p1;
#pragma unroll
        for (int m = 1; m < 16; m <<= 1) sum += __shfl_xor(sum, m, 64);
        l_run[rf][r] = l_run[rf][r] * al + sum;
        m_run[rf][r] = mnew;
        alpha[r] = al;
        p[rf][0][r] = p0; p[rf][1][r] = p1;
      }
#pragma unroll
      for (int j = 0; j < 8; ++j)
#pragma unroll
        for (int r = 0; r < 4; ++r) acc[rf][j][r] *= alpha[r];
    }
#pragma unroll
    for (int rf = 0; rf < 2; ++rf)
#pragma unroll
      for (int c = 0; c < 2; ++c)
#pragma unroll
        for (int r = 0; r < 4; ++r)
          P_lds[rf][lg * 4 + r][c * 16 + lr] = (bf16)p[rf][c][r];
    __syncthreads();
    bf16x8 pa0 = *(const bf16x8*)&P_lds[0][lr][lg * 8];
    bf16x8 pa1 = *(const bf16x8*)&P_lds[1][lr][lg * 8];
#pragma unroll
    for (int j = 0; j < 8; ++j) {
      bf16x8 bv = *(const bf16x8*)&Vt[(size_t)(h * 128 + j * 16 + lr) * 2048 + s0 + lg * 8];
      acc[0][j] = mfma16(pa0, bv, acc[0][j]);
      acc[1][j] = mfma16(pa1, bv, acc[1][j]);
    }
    __syncthreads();
  }

#pragma unroll
  for (int rf = 0; rf < 2; ++rf)
#pragma unroll
    for (int r = 0; r < 4; ++r) {
      int row = q0 + rf * 16 + lg * 4 + r;
      float inv = 1.f / l_run[rf][r];
#pragma unroll
      for (int j = 0; j < 8; ++j)
        heads[(size_t)row * 2048 + h * 128 + j * 16 + lr] = (bf16)(acc[rf][j][r] * inv);
    }
}

// ---------------------------------------------------------------- launch
extern "C" void kernel_launch(void* const* d_in, const int* in_sizes, int n_in,
                              void* d_out, int out_size, void* d_ws, size_t ws_size,
                              hipStream_t stream) {
  (void)in_sizes; (void)n_in; (void)out_size; (void)ws_size;
  const float* x      = (const float*)d_in[0];
  const float* cosp   = (const float*)d_in[1];
  const float* sinp   = (const float*)d_in[2];
  const float* Wq_d   = (const float*)d_in[3];
  const float* Wq_d_b = (const float*)d_in[4];
  const float* Wkv_d  = (const float*)d_in[5];
  const float* Wq_u   = (const float*)d_in[6];
  const float* Wk_u   = (const float*)d_in[7];
  const float* Wv_u   = (const float*)d_in[8];
  const float* W_qr   = (const float*)d_in[9];
  const float* W_kr   = (const float*)d_in[10];
  const float* W_out  = (const float*)d_in[11];

  char* ws = (char*)d_ws;
  size_t off = 0;
  auto alloc = [&](size_t bytes) {
    char* p = ws + off;
    off += (bytes + 255) & ~(size_t)255;
    return p;
  };
  bf16* xb    = (bf16*)alloc((size_t)2048 * 2048 * 2);  // reused as Vt after G1
  bf16* Wcat  = (bf16*)alloc((size_t)2176 * 2048 * 2);  // [Wq_d;Wkv_d;W_kr;pad]
  bf16* c_all = (bf16*)alloc((size_t)2048 * 2176 * 2);  // [cq|ckv|kr_pre|pad]
  bf16* Wqu   = (bf16*)alloc((size_t)3072 * 1536 * 2);  // [Wq_u;W_qr]; reused as heads
  bf16* QA    = (bf16*)alloc((size_t)2048 * 3072 * 2);  // [Qfull|Qr_pre]
  bf16* Wkvu  = (bf16*)alloc((size_t)4096 * 512 * 2);   // [Wk_u;Wv_u]
  bf16* KV    = (bf16*)alloc((size_t)2048 * 4096 * 2);  // [Kfull|Vfull]
  bf16* Qr    = (bf16*)alloc((size_t)2048 * 1024 * 2);
  bf16* Kr    = (bf16*)alloc((size_t)2048 * 64 * 2);
  bf16* Wout  = (bf16*)alloc((size_t)2048 * 2048 * 2);
  bf16* Vt    = xb;     // 8.39 MB region, free after G1
  bf16* heads = Wqu;    // 9.44 MB region, free after G2

  auto cvt = [&](const float* s, bf16* d, size_t n) {
    int n4 = (int)(n / 4);
    int grid = (n4 + 255) / 256; if (grid > 2048) grid = 2048;
    cvt_f32_bf16<<<grid, 256, 0, stream>>>(s, d, n4);
  };
  cvt(x,     xb,                          (size_t)2048 * 2048);
  cvt(Wq_d,  Wcat,                        (size_t)1536 * 2048);
  cvt(Wkv_d, Wcat + (size_t)1536 * 2048,  (size_t)512 * 2048);
  cvt(W_kr,  Wcat + (size_t)2048 * 2048,  (size_t)64 * 2048);
  cvt(Wq_u,  Wqu,                         (size_t)2048 * 1536);
  cvt(W_qr,  Wqu + (size_t)2048 * 1536,   (size_t)1024 * 1536);
  cvt(Wk_u,  Wkvu,                        (size_t)2048 * 512);
  cvt(Wv_u,  Wkvu + (size_t)2048 * 512,   (size_t)2048 * 512);
  cvt(W_out, Wout,                        (size_t)2048 * 2048);

  // G1: c_all = x @ [Wq_d;Wkv_d;W_kr]^T + bias(cols<1536)
  gemm_bt<false><<<dim3(17, 16), 256, 0, stream>>>(xb, 2048, Wcat, 2048,
                                                   nullptr, c_all, 2176, Wq_d_b, 1536);
  // G2: QA = cq @ [Wq_u;W_qr]^T
  gemm_bt<false><<<dim3(24, 16), 256, 0, stream>>>(c_all, 2176, Wqu, 1536,
                                                   nullptr, QA, 3072, nullptr, 0);
  // G3: KV = ckv @ [Wk_u;Wv_u]^T
  gemm_bt<false><<<dim3(32, 16), 256, 0, stream>>>(c_all + 1536, 2176, Wkvu, 512,
                                                   nullptr, KV, 4096, nullptr, 0);
  rope_kernel<<<2048, 256, 0, stream>>>(QA, c_all, cosp, sinp, Qr, Kr);
  transpose_v<<<dim3(64, 64), 256, 0, stream>>>(KV, Vt);
  attn_kernel<<<dim3(64, 16), 64, 0, stream>>>(QA, Qr, KV, Kr, Vt, heads);
  // G4: out = heads @ W_out^T  (f32 to d_out)
  gemm_bt<true><<<dim3(16, 16), 256, 0, stream>>>(heads, 2048, Wout, 2048,
                                                  (float*)d_out, nullptr, 2048, nullptr, 0);
}

// Round 2
// 392.929 us; speedup vs baseline: 1.2802x; 1.2802x over previous
//
#include <hip/hip_runtime.h>
#include <math.h>
#include <stdint.h>
#include <stddef.h>

typedef __bf16 bf16;
typedef __bf16 bf16x8 __attribute__((ext_vector_type(8)));
typedef __bf16 bf16x4 __attribute__((ext_vector_type(4)));
typedef float  f32x4  __attribute__((ext_vector_type(4)));
typedef float  f32x4v __attribute__((ext_vector_type(4)));

typedef __attribute__((address_space(1))) const void* as1cv;
typedef __attribute__((address_space(3))) void*       as3v;

__device__ __forceinline__ f32x4 mfma16(bf16x8 a, bf16x8 b, f32x4 c) {
  return __builtin_amdgcn_mfma_f32_16x16x32_bf16(a, b, c, 0, 0, 0);
}

__device__ __forceinline__ void gload_lds16(const bf16* g, bf16* l) {
  __builtin_amdgcn_global_load_lds((as1cv)g, (as3v)l, 16, 0, 0);
}

// ---------------------------------------------------------------- fused convert
struct CvtTable {
  const float* s[9];
  bf16* d[9];
  int cum[10];   // cumulative float4 counts
};

__global__ void cvt_all(CvtTable T, int total4) {
  int i = blockIdx.x * blockDim.x + threadIdx.x;
  int stride = gridDim.x * blockDim.x;
  for (; i < total4; i += stride) {
    int k = 0;
#pragma unroll
    for (int j = 1; j < 9; ++j) k += (i >= T.cum[j]) ? 1 : 0;
    int off = i - T.cum[k];
    f32x4v v = ((const f32x4v*)T.s[k])[off];
    bf16x4 o;
    o[0] = (bf16)v[0]; o[1] = (bf16)v[1]; o[2] = (bf16)v[2]; o[3] = (bf16)v[3];
    ((bf16x4*)T.d[k])[off] = o;
  }
}

// ---------------------------------------------------------------- GEMM  C = A @ B^T
// 128x128 tile, BK=64, double-buffered LDS, 2-phase pipeline:
// issue stage(t+1) -> compute(t) -> barrier (drains vmcnt+lgkm) -> swap.
template<bool OUTF32>
__global__ __launch_bounds__(256) void gemm_bt(
    const bf16* __restrict__ A, int lda,
    const bf16* __restrict__ B, int K,
    float* __restrict__ Cf, bf16* __restrict__ Cb, int ldc,
    const float* __restrict__ bias, int bias_n)
{
  __shared__ __align__(16) bf16 Al[2][128 * 64];
  __shared__ __align__(16) bf16 Bl[2][128 * 64];
  const int tid = threadIdx.x;
  const int l = tid & 63;
  const int wid = tid >> 6;
  const int wr = wid >> 1, wc = wid & 1;
  const int m0 = blockIdx.y * 128, n0 = blockIdx.x * 128;
  const int lr = l & 15, lg = l >> 4;

  auto STAGE = [&](int b, int k0) {
#pragma unroll
    for (int it = 0; it < 4; ++it) {
      int chunk = it * 256 + tid;          // 1024 chunks of 16B (128 rows x 8)
      int row = chunk >> 3;
      int scb = (chunk & 7) ^ (row & 7);   // inverse-swizzled source chunk
      gload_lds16(A + (size_t)(m0 + row) * lda + k0 + scb * 8, &Al[b][chunk * 8]);
    }
#pragma unroll
    for (int it = 0; it < 4; ++it) {
      int chunk = it * 256 + tid;
      int row = chunk >> 3;
      int scb = (chunk & 7) ^ (row & 7);
      gload_lds16(B + (size_t)(n0 + row) * K + k0 + scb * 8, &Bl[b][chunk * 8]);
    }
  };

  f32x4 z = {0.f, 0.f, 0.f, 0.f};
  f32x4 acc[4][4];
#pragma unroll
  for (int i = 0; i < 4; ++i)
#pragma unroll
    for (int j = 0; j < 4; ++j) acc[i][j] = z;

  STAGE(0, 0);
  __syncthreads();
  int cur = 0;
  for (int k0 = 0; k0 < K; k0 += 64) {
    if (k0 + 64 < K) STAGE(cur ^ 1, k0 + 64);
#pragma unroll
    for (int kk = 0; kk < 2; ++kk) {
      bf16x8 af[4], bfr[4];
#pragma unroll
      for (int i = 0; i < 4; ++i) {
        int row = wr * 64 + i * 16 + lr;
        int cq = kk * 4 + lg;
        af[i] = *(const bf16x8*)(&Al[cur][row * 64 + ((cq ^ (row & 7)) * 8)]);
      }
#pragma unroll
      for (int j = 0; j < 4; ++j) {
        int row = wc * 64 + j * 16 + lr;
        int cq = kk * 4 + lg;
        bfr[j] = *(const bf16x8*)(&Bl[cur][row * 64 + ((cq ^ (row & 7)) * 8)]);
      }
#pragma unroll
      for (int i = 0; i < 4; ++i)
#pragma unroll
        for (int j = 0; j < 4; ++j)
          acc[i][j] = mfma16(af[i], bfr[j], acc[i][j]);
    }
    __syncthreads();
    cur ^= 1;
  }

#pragma unroll
  for (int i = 0; i < 4; ++i)
#pragma unroll
    for (int j = 0; j < 4; ++j)
#pragma unroll
      for (int r = 0; r < 4; ++r) {
        int row = m0 + wr * 64 + i * 16 + lg * 4 + r;
        int col = n0 + wc * 64 + j * 16 + lr;
        float v = acc[i][j][r];
        if (bias != nullptr && col < bias_n) v += bias[col];
        if (OUTF32) Cf[(size_t)row * ldc + col] = v;
        else        Cb[(size_t)row * ldc + col] = (bf16)v;
      }
}

// ---------------------------------------------------------------- RoPE
__global__ void rope_kernel(const bf16* __restrict__ QA, const bf16* __restrict__ c_all,
                            const float* __restrict__ cosb, const float* __restrict__ sinb,
                            bf16* __restrict__ Qr, bf16* __restrict__ Kr)
{
  int t = blockIdx.x;
  for (int idx = threadIdx.x; idx < 544; idx += 256) {
    if (idx < 512) {
      int h = idx >> 5, p = idx & 31;
      float x1 = (float)QA[(size_t)t * 3072 + 2048 + h * 64 + p];
      float x2 = (float)QA[(size_t)t * 3072 + 2048 + h * 64 + 32 + p];
      float c = cosb[t * 32 + p], s = sinb[t * 32 + p];
      Qr[(size_t)t * 1024 + h * 64 + p]      = (bf16)( x1 * c + x2 * s);
      Qr[(size_t)t * 1024 + h * 64 + 32 + p] = (bf16)(-x1 * s + x2 * c);
    } else {
      int p = idx - 512;
      float x1 = (float)c_all[(size_t)t * 2176 + 2048 + p];
      float x2 = (float)c_all[(size_t)t * 2176 + 2048 + 32 + p];
      float c = cosb[t * 32 + p], s = sinb[t * 32 + p];
      Kr[(size_t)t * 64 + p]      = (bf16)( x1 * c + x2 * s);
      Kr[(size_t)t * 64 + 32 + p] = (bf16)(-x1 * s + x2 * c);
    }
  }
}

// ---------------------------------------------------------------- V transpose
__global__ void transpose_v(const bf16* __restrict__ KV, bf16* __restrict__ Vt) {
  __shared__ bf16 tile[32][33];
  int tx = threadIdx.x & 31, ty = threadIdx.x >> 5;
  int t0 = blockIdx.x * 32, c0 = blockIdx.y * 32;
#pragma unroll
  for (int r = 0; r < 4; ++r)
    tile[ty + r * 8][tx] = KV[(size_t)(t0 + ty + r * 8) * 4096 + 2048 + c0 + tx];
  __syncthreads();
#pragma unroll
  for (int r = 0; r < 4; ++r)
    Vt[(size_t)(c0 + ty + r * 8) * 2048 + t0 + tx] = tile[tx][ty + r * 8];
}

// ---------------------------------------------------------------- flash attention
// 4 waves/block, 16 q-rows/wave (64 rows/block), KT=32 keys/iter.
// K/Kr/V double-buffered in LDS (XOR-swizzled, staged via pre-swizzled
// global_load_lds source), 2-phase pipeline, XCD-clustered heads.
__global__ __launch_bounds__(256) void attn_kernel(
    const bf16* __restrict__ QA,  // 2048 x 3072
    const bf16* __restrict__ Qr,  // 2048 x 1024
    const bf16* __restrict__ KV,  // 2048 x 4096 ([Kfull|Vfull])
    const bf16* __restrict__ Kr,  // 2048 x 64
    const bf16* __restrict__ Vt,  // 2048(c) x 2048(t)
    bf16* __restrict__ heads)     // 2048 x 2048
{
  __shared__ __align__(16) bf16 Kl[2][32 * 128];
  __shared__ __align__(16) bf16 Krl[2][32 * 64];
  __shared__ __align__(16) bf16 Vl[2][128 * 32];
  __shared__ __align__(16) bf16 Pl[4][16 * 32];

  const int tid = threadIdx.x;
  const int l = tid & 63;
  const int wid = tid >> 6;
  const int lr = l & 15, lg = l >> 4;

  // XCD clustering: 2 heads per XCD, longest q-tiles first.
  const int wg = blockIdx.x;           // 0..511
  const int xcd = wg & 7, inx = wg >> 3;
  const int h = xcd * 2 + (inx >> 5);
  const int qb = 31 - (inx & 31);
  const int q0 = qb * 64 + wid * 16;

  const float scale = 0.041666666666666664f;  // 1/sqrt(576)
  f32x4 z = {0.f, 0.f, 0.f, 0.f};

  auto STAGE = [&](int b, int s0) {
#pragma unroll
    for (int it = 0; it < 2; ++it) {        // Kl: 512 chunks (32 rows x 16)
      int ch = it * 256 + tid;
      int r = ch >> 4, p = ch & 15;
      int cb = (p & 8) | ((p & 7) ^ (r & 7));
      gload_lds16(&KV[(size_t)(s0 + r) * 4096 + h * 128 + cb * 8], &Kl[b][ch * 8]);
    }
    {                                       // Krl: 256 chunks (32 rows x 8)
      int ch = tid;
      int r = ch >> 3, p = ch & 7;
      int cb = p ^ (r & 7);
      gload_lds16(&Kr[(size_t)(s0 + r) * 64 + cb * 8], &Krl[b][ch * 8]);
    }
#pragma unroll
    for (int it = 0; it < 2; ++it) {        // Vl: 512 chunks (128 rows x 4)
      int ch = it * 256 + tid;
      int r = ch >> 2, p = ch & 3;
      int cb = p ^ ((r >> 1) & 3);
      gload_lds16(&Vt[(size_t)(h * 128 + r) * 2048 + s0 + cb * 8], &Vl[b][ch * 8]);
    }
  };

  // Q fragments: rows q0..q0+15, K-dim 192 = 6 x 32
  bf16x8 aq[6];
#pragma unroll
  for (int kc = 0; kc < 4; ++kc)
    aq[kc] = *(const bf16x8*)&QA[(size_t)(q0 + lr) * 3072 + h * 128 + kc * 32 + lg * 8];
#pragma unroll
  for (int kc = 4; kc < 6; ++kc)
    aq[kc] = *(const bf16x8*)&Qr[(size_t)(q0 + lr) * 1024 + h * 64 + (kc - 4) * 32 + lg * 8];

  float m_run[4], l_run[4];
  f32x4 acc[8];
#pragma unroll
  for (int r = 0; r < 4; ++r) { m_run[r] = -1e30f; l_run[r] = 0.f; }
#pragma unroll
  for (int j = 0; j < 8; ++j) acc[j] = z;

  const int nIter = 2 * qb + 2;
  STAGE(0, 0);
  __syncthreads();
  int cur = 0;
  for (int st = 0; st < nIter; ++st) {
    const int s0 = st * 32;
    if (st + 1 < nIter) STAGE(cur ^ 1, s0 + 32);
    if (s0 <= q0 + 15) {                    // wave-uniform activity mask
      f32x4 sc0 = z, sc1 = z;
#pragma unroll
      for (int kc = 0; kc < 6; ++kc) {
        bf16x8 b0, b1;
        int r0 = lr, r1 = 16 + lr;
        if (kc < 4) {
          int cbl = kc * 4 + lg;
          b0 = *(const bf16x8*)&Kl[cur][r0 * 128 + (((cbl & 8) | ((cbl & 7) ^ (r0 & 7))) * 8)];
          b1 = *(const bf16x8*)&Kl[cur][r1 * 128 + (((cbl & 8) | ((cbl & 7) ^ (r1 & 7))) * 8)];
        } else {
          int cbl = (kc - 4) * 4 + lg;
          b0 = *(const bf16x8*)&Krl[cur][r0 * 64 + ((cbl ^ (r0 & 7)) * 8)];
          b1 = *(const bf16x8*)&Krl[cur][r1 * 64 + ((cbl ^ (r1 & 7)) * 8)];
        }
        sc0 = mfma16(aq[kc], b0, sc0);
        sc1 = mfma16(aq[kc], b1, sc1);
      }
      float alpha[4], e0v[4], e1v[4];
#pragma unroll
      for (int r = 0; r < 4; ++r) {
        int q = q0 + lg * 4 + r;
        float v0 = sc0[r] * scale;
        float v1 = sc1[r] * scale;
        if (s0 + lr > q)      v0 = -1e30f;
        if (s0 + 16 + lr > q) v1 = -1e30f;
        float mx = fmaxf(v0, v1);
#pragma unroll
        for (int m = 1; m < 16; m <<= 1) mx = fmaxf(mx, __shfl_xor(mx, m, 64));
        float mnew = fmaxf(m_run[r], mx);
        float al = __expf(m_run[r] - mnew);
        float e0 = __expf(v0 - mnew);
        float e1 = __expf(v1 - mnew);
        float sum = e0 + e1;
#pragma unroll
        for (int m = 1; m < 16; m <<= 1) sum += __shfl_xor(sum, m, 64);
        l_run[r] = l_run[r] * al + sum;
        m_run[r] = mnew;
        alpha[r] = al; e0v[r] = e0; e1v[r] = e1;
      }
#pragma unroll
      for (int j = 0; j < 8; ++j)
#pragma unroll
        for (int r = 0; r < 4; ++r) acc[j][r] *= alpha[r];
      // P -> per-wave LDS (swizzled), then A-frag read (in-order DS, no barrier)
#pragma unroll
      for (int r = 0; r < 4; ++r) {
        int q = lg * 4 + r;
        int sw = (q >> 1) & 3;
        int cb0 = (lr >> 3),     p0 = cb0 ^ sw;
        int cb1 = 2 + (lr >> 3), p1 = cb1 ^ sw;
        Pl[wid][q * 32 + p0 * 8 + (lr & 7)] = (bf16)e0v[r];
        Pl[wid][q * 32 + p1 * 8 + (lr & 7)] = (bf16)e1v[r];
      }
      bf16x8 pa = *(const bf16x8*)&Pl[wid][lr * 32 + ((lg ^ ((lr >> 1) & 3)) * 8)];
#pragma unroll
      for (int j = 0; j < 8; ++j) {
        int rv = j * 16 + lr;
        bf16x8 bv = *(const bf16x8*)&Vl[cur][rv * 32 + ((lg ^ ((rv >> 1) & 3)) * 8)];
        acc[j] = mfma16(pa, bv, acc[j]);
      }
    }
    __syncthreads();
    cur ^= 1;
  }

#pragma unroll
  for (int r = 0; r < 4; ++r) {
    int row = q0 + lg * 4 + r;
    float inv = 1.f / l_run[r];
#pragma unroll
    for (int j = 0; j < 8; ++j)
      heads[(size_t)row * 2048 + h * 128 + j * 16 + lr] = (bf16)(acc[j][r] * inv);
  }
}

// ---------------------------------------------------------------- launch
extern "C" void kernel_launch(void* const* d_in, const int* in_sizes, int n_in,
                              void* d_out, int out_size, void* d_ws, size_t ws_size,
                              hipStream_t stream) {
  (void)in_sizes; (void)n_in; (void)out_size; (void)ws_size;
  const float* x      = (const float*)d_in[0];
  const float* cosp   = (const float*)d_in[1];
  const float* sinp   = (const float*)d_in[2];
  const float* Wq_d   = (const float*)d_in[3];
  const float* Wq_d_b = (const float*)d_in[4];
  const float* Wkv_d  = (const float*)d_in[5];
  const float* Wq_u   = (const float*)d_in[6];
  const float* Wk_u   = (const float*)d_in[7];
  const float* Wv_u   = (const float*)d_in[8];
  const float* W_qr   = (const float*)d_in[9];
  const float* W_kr   = (const float*)d_in[10];
  const float* W_out  = (const float*)d_in[11];

  char* ws = (char*)d_ws;
  size_t off = 0;
  auto alloc = [&](size_t bytes) {
    char* p = ws + off;
    off += (bytes + 255) & ~(size_t)255;
    return p;
  };
  bf16* xb    = (bf16*)alloc((size_t)2048 * 2048 * 2);  // reused as Vt after G1
  bf16* Wcat  = (bf16*)alloc((size_t)2176 * 2048 * 2);
  bf16* c_all = (bf16*)alloc((size_t)2048 * 2176 * 2);
  bf16* Wqu   = (bf16*)alloc((size_t)3072 * 1536 * 2);  // reused as heads
  bf16* QA    = (bf16*)alloc((size_t)2048 * 3072 * 2);
  bf16* Wkvu  = (bf16*)alloc((size_t)4096 * 512 * 2);
  bf16* KV    = (bf16*)alloc((size_t)2048 * 4096 * 2);
  bf16* Qr    = (bf16*)alloc((size_t)2048 * 1024 * 2);
  bf16* Kr    = (bf16*)alloc((size_t)2048 * 64 * 2);
  bf16* Wout  = (bf16*)alloc((size_t)2048 * 2048 * 2);
  bf16* Vt    = xb;
  bf16* heads = Wqu;

  CvtTable T;
  const float* srcs[9] = { x, Wq_d, Wkv_d, W_kr, Wq_u, W_qr, Wk_u, Wv_u, W_out };
  bf16* dsts[9] = { xb, Wcat, Wcat + (size_t)1536 * 2048, Wcat + (size_t)2048 * 2048,
                    Wqu, Wqu + (size_t)2048 * 1536, Wkvu, Wkvu + (size_t)2048 * 512, Wout };
  size_t ns[9] = { (size_t)2048 * 2048, (size_t)1536 * 2048, (size_t)512 * 2048,
                   (size_t)64 * 2048, (size_t)2048 * 1536, (size_t)1024 * 1536,
                   (size_t)2048 * 512, (size_t)2048 * 512, (size_t)2048 * 2048 };
  int cum = 0;
  for (int i = 0; i < 9; ++i) {
    T.s[i] = srcs[i]; T.d[i] = dsts[i]; T.cum[i] = cum;
    cum += (int)(ns[i] / 4);
  }
  T.cum[9] = cum;
  cvt_all<<<2048, 256, 0, stream>>>(T, cum);

  // G1: c_all = x @ [Wq_d;Wkv_d;W_kr]^T + bias(cols<1536)
  gemm_bt<false><<<dim3(17, 16), 256, 0, stream>>>(xb, 2048, Wcat, 2048,
                                                   nullptr, c_all, 2176, Wq_d_b, 1536);
  // G2: QA = cq @ [Wq_u;W_qr]^T
  gemm_bt<false><<<dim3(24, 16), 256, 0, stream>>>(c_all, 2176, Wqu, 1536,
                                                   nullptr, QA, 3072, nullptr, 0);
  // G3: KV = ckv @ [Wk_u;Wv_u]^T
  gemm_bt<false><<<dim3(32, 16), 256, 0, stream>>>(c_all + 1536, 2176, Wkvu, 512,
                                                   nullptr, KV, 4096, nullptr, 0);
  rope_kernel<<<2048, 256, 0, stream>>>(QA, c_all, cosp, sinp, Qr, Kr);
  transpose_v<<<dim3(64, 64), 256, 0, stream>>>(KV, Vt);
  attn_kernel<<<512, 256, 0, stream>>>(QA, Qr, KV, Kr, Vt, heads);
  // G4: out = heads @ W_out^T  (f32 to d_out)
  gemm_bt<true><<<dim3(16, 16), 256, 0, stream>>>(heads, 2048, Wout, 2048,
                                                  (float*)d_out, nullptr, 2048, nullptr, 0);
}